// Round 5
// baseline (10864.719 us; speedup 1.0000x reference)
//
#include <hip/hip_runtime.h>
#include <cstdint>
#include <cstddef>

// ---------------------------------------------------------------------------
// 2-layer LSTM (B=256, S=1024, V=H=256) + FC + log_softmax, MI355X/gfx950.
//
// Round 5: back to sentinel-data-as-flag (R3 protocol), but consumers spin
// DIRECTLY on their MFMA A-fragment dwords in registers. No LDS, no barriers
// in the recurrence. ih-MFMA hoisted off the critical path (L0: x-based,
// precomputed before spin; L1: h1[t] always ready since L0 runs ahead).
// Critical chain per step: publish -> visible -> detect -> hh-MFMA -> gates.
//
// Phases: pack_w x5 -> memset h1/h2 sentinels -> lstm_dual -> fc_lsm.
// Workspace ~271 MB: packed weights (2.2MB) | h1 (134MB) | h2 (134MB)
// ---------------------------------------------------------------------------

typedef __attribute__((ext_vector_type(8))) short bf16x8;
typedef __attribute__((ext_vector_type(4))) float f32x4;

#define DEVFN __device__ __forceinline__

constexpr unsigned SENT = 0xFFFFFFFFu;   // bf16 NaN pair: unreachable for tanh outputs

DEVFN unsigned short f2bf(float f) {
  union { float f; unsigned u; } v; v.f = f;
  unsigned r = v.u + 0x7FFFu + ((v.u >> 16) & 1u);   // RNE
  return (unsigned short)(r >> 16);
}
DEVFN float sigm(float x) { return __builtin_amdgcn_rcpf(1.f + __expf(-x)); }
DEVFN float tanhfast(float x) {
  float ax = fabsf(x);
  float e  = __expf(-2.f * ax);
  float t  = (1.f - e) * __builtin_amdgcn_rcpf(1.f + e);
  return copysignf(t, x);
}

DEVFN unsigned aload(const unsigned* p) {
  return __hip_atomic_load(p, __ATOMIC_RELAXED, __HIP_MEMORY_SCOPE_AGENT);
}
DEVFN void astore(unsigned* p, unsigned v) {
  __hip_atomic_store(p, v, __ATOMIC_RELAXED, __HIP_MEMORY_SCOPE_AGENT);
}

DEVFN bf16x8 frag_of(unsigned d0, unsigned d1, unsigned d2, unsigned d3) {
  union { uint4 u; bf16x8 v; } t;
  t.u = make_uint4(d0, d1, d2, d3);
  return t.v;
}

// Flat sentinel spin over 32 A-fragment dwords (8 frags x 4 dwords).
// dword index within the row for slot i: (i>>2)*16 + hi4 + (i&3).
// hv[] must hold an initial batch on entry; reload-all per round (idempotent).
DEVFN void spin32(unsigned hv[32], const unsigned* base, int hi4) {
  while (true) {
    unsigned pend = 0;
#pragma unroll
    for (int i = 0; i < 32; ++i) pend |= (hv[i] == SENT) ? 1u : 0u;
    if (!pend) break;
#pragma unroll
    for (int i = 0; i < 32; ++i)
      hv[i] = aload(base + (i >> 2) * 16 + hi4 + (i & 3));
  }
}

// --------------------------------------------------------------------------
// Pack W[col][k] (K=256) into B-fragment tiles:
//   dst[((nt*8+kt)*64+lane)*8 + j] = bf16( W[nt*16+(lane&15)][kt*32+(lane>>4)*8+j] )
// grid = (ncols/16)*8 blocks of 64 threads.
// --------------------------------------------------------------------------
__global__ void pack_w(const float* __restrict__ w, unsigned short* __restrict__ dst) {
  int bid = blockIdx.x;           // nt*8 + kt
  int lane = threadIdx.x;
  int col = (bid >> 3) * 16 + (lane & 15);
  int k0  = (bid & 7) * 32 + (lane >> 4) * 8;
  const float* src = w + (size_t)col * 256 + k0;
  unsigned short* d = dst + ((size_t)bid * 64 + lane) * 8;
#pragma unroll
  for (int j = 0; j < 8; ++j) d[j] = f2bf(src[j]);
}

// --------------------------------------------------------------------------
// Dual-layer persistent LSTM. grid = 256 WGs x 128 thr (2 independent waves;
// no barriers, no LDS). bid<128: layer 0; bid>=128: layer 1. b = bid&127,
// m = b&15 (batch group), n = b>>4 (unit slice), wave w: u16 = n*2+w.
// Each wave owns 16 units x all 4 gates for 16 batch rows; W_ih/W_hh
// fragments register-resident. h exchange: relaxed agent stores into
// sentinel-initialized h buffers; consumer lanes spin directly on the
// dwords of their own A-fragments (row = lane&15, chunks of 16B).
// h layout: [S][256 b][256 u] bf16.
// --------------------------------------------------------------------------
__global__ __launch_bounds__(128, 1) void lstm_dual(
    const float* __restrict__ x,
    const unsigned short* __restrict__ Wih0, const unsigned short* __restrict__ Whh0,
    const float* __restrict__ bih0, const float* __restrict__ bhh0,
    const unsigned short* __restrict__ Wih1, const unsigned short* __restrict__ Whh1,
    const float* __restrict__ bih1, const float* __restrict__ bhh1,
    unsigned short* __restrict__ h1, unsigned short* __restrict__ h2)
{
  const int tid = threadIdx.x;
  const int w = tid >> 6, lane = tid & 63;
  const bool isL1 = blockIdx.x >= 128;
  const int b = (int)blockIdx.x & 127;
  const int m = b & 15, n = b >> 4;
  const int u16 = n * 2 + w;            // unit-tile 0..15
  const int u   = u16 * 16 + (lane & 15);
  const int r0  = (lane >> 4) * 4;      // first of this lane's 4 C rows
  const int row = lane & 15;            // A-fragment row (batch 16m+row)
  const int hi4 = (lane >> 4) * 4;      // A-fragment k-subblock (dwords)

  const unsigned short* Wih = isL1 ? Wih1 : Wih0;
  const unsigned short* Whh = isL1 ? Whh1 : Whh0;
  const float* bihp = isL1 ? bih1 : bih0;
  const float* bhhp = isL1 ? bhh1 : bhh0;

  // register-resident weight B-fragments: nt = g*16 + u16
  bf16x8 bwih[4][8], bwhh[4][8];
#pragma unroll
  for (int g = 0; g < 4; ++g)
#pragma unroll
    for (int kt = 0; kt < 8; ++kt) {
      bwih[g][kt] = *(const bf16x8*)(Wih +
          ((((size_t)(g * 16 + u16)) * 8 + kt) * 64 + lane) * 8);
      bwhh[g][kt] = *(const bf16x8*)(Whh +
          ((((size_t)(g * 16 + u16)) * 8 + kt) * 64 + lane) * 8);
    }

  float bias[4];
#pragma unroll
  for (int g = 0; g < 4; ++g) bias[g] = bihp[g * 256 + u] + bhhp[g * 256 + u];

  float c[4] = {0.f, 0.f, 0.f, 0.f};

  if (!isL1) {
    // ---------------- layer 0 (h1 recurrence; ih from x, off-chain) -------
    for (int t = 0; t < 1024; ++t) {
      // issue h1[t-1] fragment batch first (critical chain)
      unsigned hv[32];
      const unsigned* hb = nullptr;
      if (t > 0) {
        hb = (const unsigned*)h1 + ((size_t)(t - 1) * 256 + 16 * m + row) * 128;
#pragma unroll
        for (int i = 0; i < 32; ++i)
          hv[i] = aload(hb + (i >> 2) * 16 + hi4 + (i & 3));
      }

      // x[t] fragments: load f32, convert to bf16 (h-independent)
      bf16x8 xa[8];
      {
        const float* xb = x + ((size_t)(16 * m + row) * 1024 + (size_t)t) * 256 + (hi4 * 2);
#pragma unroll
        for (int kt = 0; kt < 8; ++kt) {
          float4 f0 = *(const float4*)(xb + kt * 32);
          float4 f1 = *(const float4*)(xb + kt * 32 + 4);
          unsigned d0 = f2bf(f0.x) | ((unsigned)f2bf(f0.y) << 16);
          unsigned d1 = f2bf(f0.z) | ((unsigned)f2bf(f0.w) << 16);
          unsigned d2 = f2bf(f1.x) | ((unsigned)f2bf(f1.y) << 16);
          unsigned d3 = f2bf(f1.z) | ((unsigned)f2bf(f1.w) << 16);
          xa[kt] = frag_of(d0, d1, d2, d3);
        }
      }

      // ih-MFMA (overlaps peers' publish/visibility window)
      f32x4 acc[4];
#pragma unroll
      for (int g = 0; g < 4; ++g) acc[g] = (f32x4){0.f, 0.f, 0.f, 0.f};
#pragma unroll
      for (int kt = 0; kt < 8; ++kt) {
#pragma unroll
        for (int g = 0; g < 4; ++g)
          acc[g] = __builtin_amdgcn_mfma_f32_16x16x32_bf16(xa[kt], bwih[g][kt], acc[g], 0, 0, 0);
      }

      if (t > 0) {
        spin32(hv, hb, hi4);             // detect h1[t-1]
#pragma unroll
        for (int kt = 0; kt < 8; ++kt) { // hh-MFMA (critical)
          bf16x8 a = frag_of(hv[kt*4], hv[kt*4+1], hv[kt*4+2], hv[kt*4+3]);
#pragma unroll
          for (int g = 0; g < 4; ++g)
            acc[g] = __builtin_amdgcn_mfma_f32_16x16x32_bf16(a, bwhh[g][kt], acc[g], 0, 0, 0);
        }
      }

      // gates + publish h1[t]
      unsigned myh[4];
#pragma unroll
      for (int q = 0; q < 4; ++q) {
        float ia = acc[0][q] + bias[0];
        float fa = acc[1][q] + bias[1];
        float ga = acc[2][q] + bias[2];
        float oa = acc[3][q] + bias[3];
        c[q] = sigm(fa) * c[q] + sigm(ia) * tanhfast(ga);
        myh[q] = (unsigned)f2bf(sigm(oa) * tanhfast(c[q]));
      }
#pragma unroll
      for (int q = 0; q < 4; ++q) {
        unsigned ov = (unsigned)__shfl_xor((int)myh[q], 1, 64);
        if ((lane & 1) == 0) {
          unsigned word = (myh[q] & 0xFFFFu) | (ov << 16);
          unsigned* hp = (unsigned*)h1 + (((size_t)t * 256 + 16 * m + r0 + q) * 256 + u) / 2;
          astore(hp, word);
        }
      }
    }
  } else {
    // ---------------- layer 1 (h2 recurrence; ih from h1, always-ready) ---
    for (int t = 0; t < 1024; ++t) {
      // issue h2[t-1] batch FIRST (critical chain), then h1[t] batch
      unsigned hv2[32], hv1[32];
      const unsigned* b2 = nullptr;
      if (t > 0) {
        b2 = (const unsigned*)h2 + ((size_t)(t - 1) * 256 + 16 * m + row) * 128;
#pragma unroll
        for (int i = 0; i < 32; ++i)
          hv2[i] = aload(b2 + (i >> 2) * 16 + hi4 + (i & 3));
      }
      const unsigned* b1 = (const unsigned*)h1 + ((size_t)t * 256 + 16 * m + row) * 128;
#pragma unroll
      for (int i = 0; i < 32; ++i)
        hv1[i] = aload(b1 + (i >> 2) * 16 + hi4 + (i & 3));

      // h1[t]: L0 runs ahead -> usually one pass, no re-issue
      spin32(hv1, b1, hi4);

      f32x4 acc[4];
#pragma unroll
      for (int g = 0; g < 4; ++g) acc[g] = (f32x4){0.f, 0.f, 0.f, 0.f};
#pragma unroll
      for (int kt = 0; kt < 8; ++kt) {   // ih-MFMA on h1[t] (off-chain)
        bf16x8 a = frag_of(hv1[kt*4], hv1[kt*4+1], hv1[kt*4+2], hv1[kt*4+3]);
#pragma unroll
        for (int g = 0; g < 4; ++g)
          acc[g] = __builtin_amdgcn_mfma_f32_16x16x32_bf16(a, bwih[g][kt], acc[g], 0, 0, 0);
      }

      if (t > 0) {
        spin32(hv2, b2, hi4);            // detect h2[t-1]
#pragma unroll
        for (int kt = 0; kt < 8; ++kt) { // hh-MFMA (critical)
          bf16x8 a = frag_of(hv2[kt*4], hv2[kt*4+1], hv2[kt*4+2], hv2[kt*4+3]);
#pragma unroll
          for (int g = 0; g < 4; ++g)
            acc[g] = __builtin_amdgcn_mfma_f32_16x16x32_bf16(a, bwhh[g][kt], acc[g], 0, 0, 0);
        }
      }

      // gates + publish h2[t]
      unsigned myh[4];
#pragma unroll
      for (int q = 0; q < 4; ++q) {
        float ia = acc[0][q] + bias[0];
        float fa = acc[1][q] + bias[1];
        float ga = acc[2][q] + bias[2];
        float oa = acc[3][q] + bias[3];
        c[q] = sigm(fa) * c[q] + sigm(ia) * tanhfast(ga);
        myh[q] = (unsigned)f2bf(sigm(oa) * tanhfast(c[q]));
      }
#pragma unroll
      for (int q = 0; q < 4; ++q) {
        unsigned ov = (unsigned)__shfl_xor((int)myh[q], 1, 64);
        if ((lane & 1) == 0) {
          unsigned word = (myh[q] & 0xFFFFu) | (ov << 16);
          unsigned* hp = (unsigned*)h2 + (((size_t)t * 256 + 16 * m + r0 + q) * 256 + u) / 2;
          astore(hp, word);
        }
      }
    }
  }
}

// --------------------------------------------------------------------------
// logits = h2 @ fc_w^T + fc_b; out = logits - logsumexp(logits) (rows of 256).
// Block = 256 thr (4 waves); tile = 64 rows (fixed t, 64 b's) x 256 cols.
// grid = 4096 (t = bid>>2, b0 = (bid&3)*64).
// --------------------------------------------------------------------------
__global__ __launch_bounds__(256, 1) void fc_lsm(
    const unsigned short* __restrict__ h2,
    const unsigned short* __restrict__ Bp,
    const float* __restrict__ fcb,
    float* __restrict__ out)
{
  const int tid = threadIdx.x;
  const int wid = tid >> 6, lane = tid & 63;
  const int t = blockIdx.x >> 2, b0 = (blockIdx.x & 3) * 64;

  f32x4 acc[16];
#pragma unroll
  for (int nt = 0; nt < 16; ++nt) acc[nt] = (f32x4){0.f, 0.f, 0.f, 0.f};

#pragma unroll
  for (int kt = 0; kt < 8; ++kt) {
    bf16x8 a = *(const bf16x8*)(h2 +
        (((size_t)t * 256 + b0 + wid * 16 + (lane & 15)) * 256 +
         kt * 32 + (lane >> 4) * 8));
#pragma unroll
    for (int nt = 0; nt < 16; ++nt) {
      bf16x8 b = *(const bf16x8*)(Bp + (((size_t)nt * 8 + kt) * 64 + lane) * 8);
      acc[nt] = __builtin_amdgcn_mfma_f32_16x16x32_bf16(a, b, acc[nt], 0, 0, 0);
    }
  }
#pragma unroll
  for (int nt = 0; nt < 16; ++nt) {
    float bias = fcb[nt * 16 + (lane & 15)];
#pragma unroll
    for (int q = 0; q < 4; ++q) acc[nt][q] += bias;
  }

  float mx[4] = {-1e30f, -1e30f, -1e30f, -1e30f};
#pragma unroll
  for (int nt = 0; nt < 16; ++nt)
#pragma unroll
    for (int q = 0; q < 4; ++q) mx[q] = fmaxf(mx[q], acc[nt][q]);
#pragma unroll
  for (int d = 1; d < 16; d <<= 1)
#pragma unroll
    for (int q = 0; q < 4; ++q) mx[q] = fmaxf(mx[q], __shfl_xor(mx[q], d, 64));

  float sm[4] = {0.f, 0.f, 0.f, 0.f};
#pragma unroll
  for (int nt = 0; nt < 16; ++nt)
#pragma unroll
    for (int q = 0; q < 4; ++q) sm[q] += __expf(acc[nt][q] - mx[q]);
#pragma unroll
  for (int d = 1; d < 16; d <<= 1)
#pragma unroll
    for (int q = 0; q < 4; ++q) sm[q] += __shfl_xor(sm[q], d, 64);

  float lse[4];
#pragma unroll
  for (int q = 0; q < 4; ++q) lse[q] = mx[q] + __logf(sm[q]);

#pragma unroll
  for (int nt = 0; nt < 16; ++nt) {
#pragma unroll
    for (int q = 0; q < 4; ++q) {
      int b = b0 + wid * 16 + (lane >> 4) * 4 + q;
      out[((size_t)b * 1024 + t) * 256 + nt * 16 + (lane & 15)] = acc[nt][q] - lse[q];
    }
  }
}

// Unambiguous marker if workspace is too small.
__global__ void fill_marker(float* out, size_t nvals) {
  size_t i = (size_t)blockIdx.x * blockDim.x + threadIdx.x;
  if (i < nvals) out[i] = -7777.0f;
}

// --------------------------------------------------------------------------
extern "C" void kernel_launch(void* const* d_in, const int* in_sizes, int n_in,
                              void* d_out, int out_size, void* d_ws, size_t ws_size,
                              hipStream_t stream)
{
  (void)in_sizes; (void)n_in;
  const float* x    = (const float*)d_in[0];
  const float* wih0 = (const float*)d_in[1];
  const float* whh0 = (const float*)d_in[2];
  const float* bih0 = (const float*)d_in[3];
  const float* bhh0 = (const float*)d_in[4];
  const float* wih1 = (const float*)d_in[5];
  const float* whh1 = (const float*)d_in[6];
  const float* bih1 = (const float*)d_in[7];
  const float* bhh1 = (const float*)d_in[8];
  const float* fcw  = (const float*)d_in[9];
  const float* fcb  = (const float*)d_in[10];
  float* out = (float*)d_out;

  // workspace layout (bytes)
  const size_t o_wp0i = 0;
  const size_t o_wp0h = o_wp0i + 524288;
  const size_t o_wp1i = o_wp0h + 524288;
  const size_t o_wp1h = o_wp1i + 524288;
  const size_t o_fcp  = o_wp1h + 524288;        // 131072
  const size_t o_h1   = o_fcp  + 131072;        // 134217728
  const size_t o_h2   = o_h1   + 134217728;     // 134217728
  const size_t need   = o_h2   + 134217728;     // ~271 MB

  if (ws_size < need) {
    size_t nv = (size_t)out_size;
    fill_marker<<<(unsigned)((nv + 1023) / 1024), 1024, 0, stream>>>(out, nv);
    return;
  }

  char* ws = (char*)d_ws;
  unsigned short* wp0i = (unsigned short*)(ws + o_wp0i);
  unsigned short* wp0h = (unsigned short*)(ws + o_wp0h);
  unsigned short* wp1i = (unsigned short*)(ws + o_wp1i);
  unsigned short* wp1h = (unsigned short*)(ws + o_wp1h);
  unsigned short* fcp  = (unsigned short*)(ws + o_fcp);
  unsigned short* h1   = (unsigned short*)(ws + o_h1);
  unsigned short* h2   = (unsigned short*)(ws + o_h2);

  pack_w<<<512, 64, 0, stream>>>(wih0, wp0i);
  pack_w<<<512, 64, 0, stream>>>(whh0, wp0h);
  pack_w<<<512, 64, 0, stream>>>(wih1, wp1i);
  pack_w<<<512, 64, 0, stream>>>(whh1, wp1h);
  pack_w<<<128, 64, 0, stream>>>(fcw,  fcp);

  // sentinel-init both h buffers (0xFF bytes -> 0xFFFFFFFF dwords)
  hipMemsetAsync(h1, 0xFF, 134217728, stream);
  hipMemsetAsync(h2, 0xFF, 134217728, stream);

  lstm_dual<<<256, 128, 0, stream>>>(x, wp0i, wp0h, bih0, bhh0,
                                     wp1i, wp1h, bih1, bhh1, h1, h2);

  fc_lsm<<<4096, 256, 0, stream>>>(h2, fcp, fcb, out);
}